// Round 10
// baseline (801.269 us; speedup 1.0000x reference)
//
#include <hip/hip_runtime.h>

// out[b,t,u] = y[b,t]*out[b,t-1,u] + x[b,t]*z[b,t,u], out[b,-1,u]=0
// in layout: [B][T][F], F=1026: x=col0, y=col1, z=cols 2..1025
//
// Single-pass chunked scan, decoupled look-back, 1 unit/thread.
// FIXES vs R8 (both latency-bound at ~520us, VGPR=52):
//  1. Chunk state = 64 INDIVIDUALLY-NAMED floats (macro-expanded straight-line
//     code, LITERAL indices -- R9's B+1 token-paste bug fixed). float[64]
//     allocas hit AMDGPU promote-alloca limits and v64f32 exceeds the max
//     32-register tuple class -> both spilled. Named scalars = SSA -> VGPRs.
//  2. Flag wait = thread0 only, one flag at a time, s_sleep(16) (~0.4us)
//     between polls. R5-R8 had up to 63 lanes x ~1000 blocks hammering
//     agent-scope loads -> fabric DDoS starving the data path.
//
// Progress guarantee: vid from atomic counter; block with vid V waits only
// on vids < V, claimed by already-started (hence resident-or-finished) blocks.

#define BB 8
#define TT 4096
#define FF 1026
#define UU 1024
#define NC 64
#define CC 64                    // TT/NC
#define USL 4                    // u-slices of 256 units
#define RPB (BB * USL)           // 32 blocks per chunk-generation
#define NBLK (NC * RPB)          // 2048 blocks

typedef float f2 __attribute__((ext_vector_type(2)));

#define R64(M) \
  M(0) M(1) M(2) M(3) M(4) M(5) M(6) M(7) \
  M(8) M(9) M(10) M(11) M(12) M(13) M(14) M(15) \
  M(16) M(17) M(18) M(19) M(20) M(21) M(22) M(23) \
  M(24) M(25) M(26) M(27) M(28) M(29) M(30) M(31) \
  M(32) M(33) M(34) M(35) M(36) M(37) M(38) M(39) \
  M(40) M(41) M(42) M(43) M(44) M(45) M(46) M(47) \
  M(48) M(49) M(50) M(51) M(52) M(53) M(54) M(55) \
  M(56) M(57) M(58) M(59) M(60) M(61) M(62) M(63)

__global__ __launch_bounds__(256) void k_onepass(const float* __restrict__ in,
                                                 float* __restrict__ out,
                                                 int* __restrict__ flags,   // [NBLK]
                                                 int* __restrict__ counter, // [1]
                                                 float* __restrict__ Agg,   // [NBLK]
                                                 float* __restrict__ Bc) {  // [NBLK][256]
    __shared__ int s_vid;
    __shared__ float s_x[CC], s_y[CC], s_suf[CC];
    if (threadIdx.x == 0) s_vid = atomicAdd(counter, 1);
    __syncthreads();
    const int vid = s_vid;
    const int c    = vid >> 5;        // chunk index (vid-major => preds earlier)
    const int base = vid & 31;        // (b, us)
    const int b    = base >> 2;
    const int us   = base & 3;
    const int tid  = threadIdx.x;
    const int u    = us * 256 + tid;

    const float* row = in + ((size_t)b * TT + (size_t)c * CC) * FF;

    // ---- phase 0: stage x,y ----
    if (tid < CC) {
        f2 xy = *reinterpret_cast<const f2*>(row + (size_t)tid * FF);
        s_x[tid] = xy.x; s_y[tid] = xy.y;
    }
    __syncthreads();

    // ---- phase 1: local scan, state in 64 NAMED registers ----
    const float* zp = row + 2 + u;
    float acc = 0.f;
#define DECL_ST(i) float st##i;
    R64(DECL_ST)
#define STEP1(i) { float z = zp[(size_t)i * FF]; \
                   acc = fmaf(s_y[i], acc, s_x[i] * z); st##i = acc; }
    R64(STEP1)

    // ---- publish aggregate (release) ----
    Bc[(size_t)vid * 256 + tid] = acc;
    if (tid == 0) {
        float yp = s_y[0];
        for (int t = 1; t < CC; ++t) yp *= s_y[t];
        Agg[vid] = yp;
    }
    __threadfence();
    __syncthreads();
    if (tid == 0)
        __hip_atomic_store(&flags[vid], 1, __ATOMIC_RELEASE, __HIP_MEMORY_SCOPE_AGENT);

    // ---- phase 2: look-back ----
    float carry = 0.f;
    if (c > 0) {
        if (tid == 0) {  // single-lane, single-address, rate-limited polling
            for (int j = 0; j < c; ++j) {
                while (__hip_atomic_load(&flags[j * 32 + base], __ATOMIC_ACQUIRE,
                                         __HIP_MEMORY_SCOPE_AGENT) == 0)
                    __builtin_amdgcn_s_sleep(16);
            }
        }
        __syncthreads();
        if (tid < c) s_suf[tid] = Agg[tid * 32 + base];
        __syncthreads();
        if (tid == 0) {  // s_suf[j] <- prod_{k=j+1}^{c-1} A_k
            float p = 1.f;
            for (int j = c - 1; j >= 0; --j) { float a = s_suf[j]; s_suf[j] = p; p *= a; }
        }
        __syncthreads();
        for (int j = 0; j < c; ++j)   // independent loads, pipelined
            carry = fmaf(s_suf[j], Bc[(size_t)(j * 32 + base) * 256 + tid], carry);
    }

    // ---- phase 3: apply carry, stream out ----
    float* orow = out + ((size_t)b * TT + (size_t)c * CC) * UU + u;
    float q = carry;
#define STEP3(i) { q *= s_y[i]; \
                   __builtin_nontemporal_store(st##i + q, orow + (size_t)i * UU); }
    R64(STEP3)
}

// ---------------- fallback (round-2 structure, proven 70.5us) ----------------
__global__ __launch_bounds__(256) void k_partial32(const float* __restrict__ in,
                                                   float* __restrict__ A,
                                                   float* __restrict__ Bc) {
    int bid = blockIdx.x, s = bid & 1, chunk = (bid >> 1) & 31, b = bid >> 6;
    int u = s * 512 + threadIdx.x * 2;
    const float* row = in + ((size_t)b * TT + (size_t)chunk * 128) * FF;
    float accx = 0.f, accy = 0.f, yprod = 1.f;
#pragma unroll 8
    for (int t = 0; t < 128; ++t) {
        f2 xy = *reinterpret_cast<const f2*>(row + (size_t)t * FF);
        f2 z  = *reinterpret_cast<const f2*>(row + (size_t)t * FF + 2 + u);
        accx = fmaf(xy.y, accx, xy.x * z.x);
        accy = fmaf(xy.y, accy, xy.x * z.y);
        yprod *= xy.y;
    }
    f2 o; o.x = accx; o.y = accy;
    *reinterpret_cast<f2*>(Bc + ((size_t)b * 32 + chunk) * UU + u) = o;
    if (threadIdx.x == 0 && s == 0) A[b * 32 + chunk] = yprod;
}
__global__ __launch_bounds__(256) void k_scan32(const float* __restrict__ A,
                                                float* __restrict__ Bc) {
    int tid = blockIdx.x * 256 + threadIdx.x;
    int b = tid / 512, u = (tid % 512) * 2;
    float cx = 0.f, cy = 0.f;
#pragma unroll
    for (int c = 0; c < 32; ++c) {
        float a = A[b * 32 + c];
        f2* p = reinterpret_cast<f2*>(Bc + ((size_t)b * 32 + c) * UU + u);
        f2 bv = *p;
        cx = fmaf(a, cx, bv.x); cy = fmaf(a, cy, bv.y);
        f2 o; o.x = cx; o.y = cy; *p = o;
    }
}
__global__ __launch_bounds__(256) void k_final32(const float* __restrict__ in,
                                                 const float* __restrict__ Bc,
                                                 float* __restrict__ out) {
    int bid = blockIdx.x, s = bid & 1, chunk = (bid >> 1) & 31, b = bid >> 6;
    int u = s * 512 + threadIdx.x * 2;
    const float* row  = in  + ((size_t)b * TT + (size_t)chunk * 128) * FF;
    float*       orow = out + ((size_t)b * TT + (size_t)chunk * 128) * UU + u;
    float accx = 0.f, accy = 0.f;
    if (chunk != 0) {
        f2 cv = *reinterpret_cast<const f2*>(Bc + ((size_t)b * 32 + chunk - 1) * UU + u);
        accx = cv.x; accy = cv.y;
    }
#pragma unroll 8
    for (int t = 0; t < 128; ++t) {
        f2 xy = *reinterpret_cast<const f2*>(row + (size_t)t * FF);
        f2 z  = *reinterpret_cast<const f2*>(row + (size_t)t * FF + 2 + u);
        accx = fmaf(xy.y, accx, xy.x * z.x);
        accy = fmaf(xy.y, accy, xy.x * z.y);
        f2 o; o.x = accx; o.y = accy;
        __builtin_nontemporal_store(o, reinterpret_cast<f2*>(orow + (size_t)t * UU));
    }
}

extern "C" void kernel_launch(void* const* d_in, const int* in_sizes, int n_in,
                              void* d_out, int out_size, void* d_ws, size_t ws_size,
                              hipStream_t stream) {
    const float* in  = (const float*)d_in[0];
    float*       out = (float*)d_out;
    char*        ws  = (char*)d_ws;

    // ws: flags[NBLK] | counter(+pad) | Agg[NBLK] | Bc[NBLK][256]
    const size_t off_counter = (size_t)NBLK * 4;                  // 8192
    const size_t off_agg     = off_counter + 128;                 // 8320
    const size_t off_bc      = off_agg + (size_t)NBLK * 4;        // 16512
    const size_t need        = off_bc + (size_t)NBLK * 256 * 4;   // ~2.02 MB

    if (ws_size >= need) {
        hipMemsetAsync(ws, 0, off_counter + 4, stream);  // flags + counter
        k_onepass<<<NBLK, 256, 0, stream>>>(
            in, out,
            (int*)ws, (int*)(ws + off_counter),
            (float*)(ws + off_agg), (float*)(ws + off_bc));
    } else {
        float* A  = (float*)ws;
        float* Bc = A + 8 * 32;
        k_partial32<<<512, 256, 0, stream>>>(in, A, Bc);
        k_scan32<<<16, 256, 0, stream>>>(A, Bc);
        k_final32<<<512, 256, 0, stream>>>(in, Bc, out);
    }
}

// Round 11
// 734.683 us; speedup vs baseline: 1.0906x; 1.0906x over previous
//
#include <hip/hip_runtime.h>

// out[b,t,u] = y[b,t]*out[b,t-1,u] + x[b,t]*z[b,t,u], out[b,-1,u]=0
// in layout: [B][T][F], F=1026: x=col0, y=col1, z=cols 2..1025
//
// One-pass chunked scan, decoupled look-back, chunk state in LDS.
// R4-R10 lesson: the compiler spills any >32-float per-thread state to
// scratch (VGPR pinned at 52 across float[64]/v64/named-scalar variants)
// -> latency-bound 500-900us. State now lives in LDS: s_st[t*256+tid],
// each thread touches only its own column (no sync needed, 2 lanes/bank
// = conflict-free). LDS round-trip 2x134MB @ 69TB/s ~ 4us aggregate.
//
// Progress guarantee (proven R4/R6/R7/R8/R10): vid from atomic counter;
// block with vid V waits only on vids < V, claimed by already-started
// (hence resident-or-finished) blocks. Flags memset per launch.

#define BB 8
#define TT 4096
#define FF 1026
#define UU 1024

typedef float f2 __attribute__((ext_vector_type(2)));

template <int NC>
__global__ __launch_bounds__(256) void k_onepass_lds(
        const float* __restrict__ in, float* __restrict__ out,
        int* __restrict__ flags,      // [NBLK]
        int* __restrict__ counter,    // [1]
        float* __restrict__ Agg,      // [NBLK]
        float* __restrict__ Bc) {     // [NBLK][256]
    constexpr int CC = TT / NC;       // timesteps per chunk
    __shared__ int   s_vid;
    __shared__ float s_x[CC], s_y[CC], s_suf[NC];
    __shared__ float s_st[CC * 256];  // chunk state: [t][tid]

    const int tid = threadIdx.x;
    if (tid == 0) s_vid = atomicAdd(counter, 1);
    __syncthreads();
    const int vid  = s_vid;
    const int c    = vid >> 5;        // chunk (vid-major => preds have smaller vid)
    const int base = vid & 31;        // (b, us)
    const int b    = base >> 2;
    const int us   = base & 3;
    const int u    = us * 256 + tid;

    const float* row = in + ((size_t)b * TT + (size_t)c * CC) * FF;

    // ---- phase 0: stage x,y ----
    if (tid < CC) {
        f2 xy = *reinterpret_cast<const f2*>(row + (size_t)tid * FF);
        s_x[tid] = xy.x; s_y[tid] = xy.y;
    }
    __syncthreads();

    // ---- phase 1: local zero-init scan, state column in LDS ----
    const float* zp = row + 2 + u;
    float acc = 0.f;
#pragma unroll
    for (int t = 0; t < CC; ++t) {
        float z = zp[(size_t)t * FF];
        acc = fmaf(s_y[t], acc, s_x[t] * z);
        s_st[t * 256 + tid] = acc;
    }

    // ---- publish aggregate (release) ----
    Bc[(size_t)vid * 256 + tid] = acc;
    if (tid == 0) {
        float yp = s_y[0];
        for (int t = 1; t < CC; ++t) yp *= s_y[t];
        Agg[vid] = yp;
    }
    __threadfence();
    __syncthreads();
    if (tid == 0)
        __hip_atomic_store(&flags[vid], 1, __ATOMIC_RELEASE, __HIP_MEMORY_SCOPE_AGENT);

    // ---- phase 2: look-back ----
    float carry = 0.f;
    if (c > 0) {
        if (tid < c) {   // parallel wait, one flag per lane
            while (__hip_atomic_load(&flags[tid * 32 + base], __ATOMIC_ACQUIRE,
                                     __HIP_MEMORY_SCOPE_AGENT) == 0)
                __builtin_amdgcn_s_sleep(1);
        }
        __syncthreads();
        if (tid < c) s_suf[tid] = Agg[tid * 32 + base];
        __syncthreads();
        if (tid == 0) {  // s_suf[j] <- prod_{k=j+1}^{c-1} A_k
            float p = 1.f;
            for (int j = c - 1; j >= 0; --j) { float a = s_suf[j]; s_suf[j] = p; p *= a; }
        }
        __syncthreads();
        // dot-product fold with 4 independent accumulators (pipelined loads)
        float c0 = 0.f, c1 = 0.f, c2 = 0.f, c3 = 0.f;
        int j = 0;
        for (; j + 3 < c; j += 4) {
            c0 = fmaf(s_suf[j + 0], Bc[(size_t)((j + 0) * 32 + base) * 256 + tid], c0);
            c1 = fmaf(s_suf[j + 1], Bc[(size_t)((j + 1) * 32 + base) * 256 + tid], c1);
            c2 = fmaf(s_suf[j + 2], Bc[(size_t)((j + 2) * 32 + base) * 256 + tid], c2);
            c3 = fmaf(s_suf[j + 3], Bc[(size_t)((j + 3) * 32 + base) * 256 + tid], c3);
        }
        for (; j < c; ++j)
            c0 = fmaf(s_suf[j], Bc[(size_t)(j * 32 + base) * 256 + tid], c0);
        carry = (c0 + c1) + (c2 + c3);
    }

    // ---- phase 3: apply carry, stream out (no input re-read) ----
    float* orow = out + ((size_t)b * TT + (size_t)c * CC) * UU + u;
    float q = carry;
#pragma unroll
    for (int t = 0; t < CC; ++t) {
        q *= s_y[t];
        __builtin_nontemporal_store(s_st[t * 256 + tid] + q, orow + (size_t)t * UU);
    }
}

// ---------------- fallback (round-2 structure, proven 70.5us) ----------------
__global__ __launch_bounds__(256) void k_partial32(const float* __restrict__ in,
                                                   float* __restrict__ A,
                                                   float* __restrict__ Bc) {
    int bid = blockIdx.x, s = bid & 1, chunk = (bid >> 1) & 31, b = bid >> 6;
    int u = s * 512 + threadIdx.x * 2;
    const float* row = in + ((size_t)b * TT + (size_t)chunk * 128) * FF;
    float accx = 0.f, accy = 0.f, yprod = 1.f;
#pragma unroll 8
    for (int t = 0; t < 128; ++t) {
        f2 xy = *reinterpret_cast<const f2*>(row + (size_t)t * FF);
        f2 z  = *reinterpret_cast<const f2*>(row + (size_t)t * FF + 2 + u);
        accx = fmaf(xy.y, accx, xy.x * z.x);
        accy = fmaf(xy.y, accy, xy.x * z.y);
        yprod *= xy.y;
    }
    f2 o; o.x = accx; o.y = accy;
    *reinterpret_cast<f2*>(Bc + ((size_t)b * 32 + chunk) * UU + u) = o;
    if (threadIdx.x == 0 && s == 0) A[b * 32 + chunk] = yprod;
}
__global__ __launch_bounds__(256) void k_scan32(const float* __restrict__ A,
                                                float* __restrict__ Bc) {
    int tid = blockIdx.x * 256 + threadIdx.x;
    int b = tid / 512, u = (tid % 512) * 2;
    float cx = 0.f, cy = 0.f;
#pragma unroll
    for (int c = 0; c < 32; ++c) {
        float a = A[b * 32 + c];
        f2* p = reinterpret_cast<f2*>(Bc + ((size_t)b * 32 + c) * UU + u);
        f2 bv = *p;
        cx = fmaf(a, cx, bv.x); cy = fmaf(a, cy, bv.y);
        f2 o; o.x = cx; o.y = cy; *p = o;
    }
}
__global__ __launch_bounds__(256) void k_final32(const float* __restrict__ in,
                                                 const float* __restrict__ Bc,
                                                 float* __restrict__ out) {
    int bid = blockIdx.x, s = bid & 1, chunk = (bid >> 1) & 31, b = bid >> 6;
    int u = s * 512 + threadIdx.x * 2;
    const float* row  = in  + ((size_t)b * TT + (size_t)chunk * 128) * FF;
    float*       orow = out + ((size_t)b * TT + (size_t)chunk * 128) * UU + u;
    float accx = 0.f, accy = 0.f;
    if (chunk != 0) {
        f2 cv = *reinterpret_cast<const f2*>(Bc + ((size_t)b * 32 + chunk - 1) * UU + u);
        accx = cv.x; accy = cv.y;
    }
#pragma unroll 8
    for (int t = 0; t < 128; ++t) {
        f2 xy = *reinterpret_cast<const f2*>(row + (size_t)t * FF);
        f2 z  = *reinterpret_cast<const f2*>(row + (size_t)t * FF + 2 + u);
        accx = fmaf(xy.y, accx, xy.x * z.x);
        accy = fmaf(xy.y, accy, xy.x * z.y);
        f2 o; o.x = accx; o.y = accy;
        __builtin_nontemporal_store(o, reinterpret_cast<f2*>(orow + (size_t)t * UU));
    }
}

extern "C" void kernel_launch(void* const* d_in, const int* in_sizes, int n_in,
                              void* d_out, int out_size, void* d_ws, size_t ws_size,
                              hipStream_t stream) {
    const float* in  = (const float*)d_in[0];
    float*       out = (float*)d_out;
    char*        ws  = (char*)d_ws;

    // ws: flags[NBLK] | counter(+pad to 128) | Agg[NBLK] | Bc[NBLK][256]
    auto offs = [](size_t nblk, size_t& o_cnt, size_t& o_agg, size_t& o_bc) {
        o_cnt = nblk * 4;
        o_agg = o_cnt + 128;
        o_bc  = o_agg + nblk * 4;
        return o_bc + nblk * 256 * 4;
    };

    size_t oc, oa, ob;
    const size_t need128 = offs(128 * 32, oc, oa, ob);   // ~4.03 MiB
    if (ws_size >= need128) {
        offs(128 * 32, oc, oa, ob);
        hipMemsetAsync(ws, 0, oc + 4, stream);
        k_onepass_lds<128><<<128 * 32, 256, 0, stream>>>(
            in, out, (int*)ws, (int*)(ws + oc), (float*)(ws + oa), (float*)(ws + ob));
        return;
    }
    const size_t need64 = offs(64 * 32, oc, oa, ob);     // ~2.02 MiB (R4-proven fit)
    if (ws_size >= need64) {
        hipMemsetAsync(ws, 0, oc + 4, stream);
        k_onepass_lds<64><<<64 * 32, 256, 0, stream>>>(
            in, out, (int*)ws, (int*)(ws + oc), (float*)(ws + oa), (float*)(ws + ob));
        return;
    }
    // last-resort: proven 3-kernel structure
    float* A  = (float*)ws;
    float* Bc = A + 8 * 32;
    k_partial32<<<512, 256, 0, stream>>>(in, A, Bc);
    k_scan32<<<16, 256, 0, stream>>>(A, Bc);
    k_final32<<<512, 256, 0, stream>>>(in, Bc, out);
}